// Round 1
// baseline (1869.694 us; speedup 1.0000x reference)
//
#include <hip/hip_runtime.h>
#include <hip/hip_bf16.h>

#define D 1024
#define NQ 8192
#define NM 32768
#define TOPK 32

typedef __attribute__((ext_vector_type(8))) __bf16 bf16x8;
typedef __attribute__((ext_vector_type(4))) float f32x4;

__device__ __forceinline__ void load_lds16(const void* g, void* l) {
  __builtin_amdgcn_global_load_lds(
      (const __attribute__((address_space(1))) void*)g,
      (__attribute__((address_space(3))) void*)l, 16, 0, 0);
}

__device__ __forceinline__ ushort f2bf(float f) {
  unsigned u = __float_as_uint(f);
  unsigned r = (u + 0x7FFFu + ((u >> 16) & 1u)) >> 16;
  return (ushort)r;
}

// monotonic float->uint key: unsigned compare order == float order
__device__ __forceinline__ unsigned fkey(float f) {
  unsigned u = __float_as_uint(f);
  return (u & 0x80000000u) ? ~u : (u | 0x80000000u);
}
__device__ __forceinline__ float kinv(unsigned k) {
  unsigned u = (k & 0x80000000u) ? (k & 0x7fffffffu) : ~k;
  return __uint_as_float(u);
}

// ---------- row L2-normalize f32 -> bf16 ----------
__global__ __launch_bounds__(256) void norm_cast_k(const float* __restrict__ in,
                                                   ushort* __restrict__ out) {
  const int row = blockIdx.x;
  const int tid = threadIdx.x;
  const float4 v = ((const float4*)(in + (size_t)row * D))[tid];
  float ss = v.x * v.x + v.y * v.y + v.z * v.z + v.w * v.w;
#pragma unroll
  for (int off = 32; off; off >>= 1) ss += __shfl_xor(ss, off, 64);
  __shared__ float wsum[4];
  const int wid = tid >> 6, lane = tid & 63;
  if (lane == 0) wsum[wid] = ss;
  __syncthreads();
  const float tot = wsum[0] + wsum[1] + wsum[2] + wsum[3];
  const float inv = 1.0f / fmaxf(sqrtf(tot), 1e-12f);
  ushort4 o;
  o.x = f2bf(v.x * inv);
  o.y = f2bf(v.y * inv);
  o.z = f2bf(v.z * inv);
  o.w = f2bf(v.w * inv);
  ((ushort4*)(out + (size_t)row * D))[tid] = o;
}

// ---------- bf16 GEMM: C[r][c] = sum_k A[r][k]*B[c][k]  (B^T layout) ----------
// 128x128 tile, BK=32, 4 waves 2x2, m97 structure (global_load_lds width 16)
__global__ __launch_bounds__(256) void gemm_qk(const ushort* __restrict__ A,   // [rows][1024]
                                               const ushort* __restrict__ B,   // [32768][1024]
                                               float* __restrict__ C) {        // [rows][32768]
  __shared__ alignas(16) ushort As[128 * 32];
  __shared__ alignas(16) ushort Bs[128 * 32];
  const int tid = threadIdx.x;
  const int lane = tid & 63, wid = tid >> 6;
  const int bx = blockIdx.x, by = blockIdx.y;
  const int wr = wid >> 1, wc = wid & 1;

  f32x4 acc[4][4];
#pragma unroll
  for (int m = 0; m < 4; m++)
#pragma unroll
    for (int n = 0; n < 4; n++) acc[m][n] = f32x4{0.f, 0.f, 0.f, 0.f};

  // staging: 512 chunks of 16B per tile; thread t handles chunks t and t+256
  const int r0 = tid >> 2;            // 0..63
  const int r1 = (tid + 256) >> 2;    // 64..127
  const int cb = (tid & 3) * 8;       // element col offset in tile
  const ushort* gA0 = A + ((size_t)by * 128 + r0) * D + cb;
  const ushort* gA1 = A + ((size_t)by * 128 + r1) * D + cb;
  const ushort* gB0 = B + ((size_t)bx * 128 + r0) * D + cb;
  const ushort* gB1 = B + ((size_t)bx * 128 + r1) * D + cb;
  // wave-uniform LDS bases (HW writes base + lane*16)
  ushort* lA0 = As + wid * 64 * 8;
  ushort* lA1 = As + 256 * 8 + wid * 64 * 8;
  ushort* lB0 = Bs + wid * 64 * 8;
  ushort* lB1 = Bs + 256 * 8 + wid * 64 * 8;

  const int aoff = (wr * 64 + (lane & 15)) * 32 + (lane >> 4) * 8;
  const int boff = (wc * 64 + (lane & 15)) * 32 + (lane >> 4) * 8;

  for (int kk = 0; kk < D; kk += 32) {
    load_lds16(gA0 + kk, lA0);
    load_lds16(gA1 + kk, lA1);
    load_lds16(gB0 + kk, lB0);
    load_lds16(gB1 + kk, lB1);
    __syncthreads();
    bf16x8 af[4], bfv[4];
#pragma unroll
    for (int m = 0; m < 4; m++) af[m] = *(const bf16x8*)&As[aoff + m * 16 * 32];
#pragma unroll
    for (int n = 0; n < 4; n++) bfv[n] = *(const bf16x8*)&Bs[boff + n * 16 * 32];
#pragma unroll
    for (int m = 0; m < 4; m++)
#pragma unroll
      for (int n = 0; n < 4; n++)
        acc[m][n] = __builtin_amdgcn_mfma_f32_16x16x32_bf16(af[m], bfv[n], acc[m][n], 0, 0, 0);
    __syncthreads();
  }

  // verified C/D layout: row = (lane>>4)*4 + j, col = lane&15
  const size_t crow = (size_t)by * 128 + wr * 64 + ((lane >> 4) << 2);
  const size_t ccol = (size_t)bx * 128 + wc * 64 + (lane & 15);
#pragma unroll
  for (int m = 0; m < 4; m++)
#pragma unroll
    for (int n = 0; n < 4; n++)
#pragma unroll
      for (int j = 0; j < 4; j++)
        C[(crow + m * 16 + j) * (size_t)NM + ccol + n * 16] = acc[m][n][j];
}

// ---------- top-32 per row via radix histogram + argmax extraction ----------
#define CAP 512
__global__ __launch_bounds__(256) void topk_k(const float* __restrict__ scores, int row_base,
                                              const float* __restrict__ temp,
                                              float* __restrict__ attn,
                                              int* __restrict__ idx_out) {
  const int lrow = blockIdx.x;
  const int grow = row_base + lrow;
  const int tid = threadIdx.x;
  __shared__ unsigned hist[2048];
  __shared__ unsigned csum[256];
  __shared__ int bstar_s;
  __shared__ int cnt_s;
  __shared__ unsigned ckey[CAP];
  __shared__ int cidx[CAP];
  __shared__ unsigned okey[TOPK];
  __shared__ int oidx[TOPK];

  for (int i = tid; i < 2048; i += 256) hist[i] = 0;
  if (tid == 0) cnt_s = 0;
  __syncthreads();

  const float4* r4 = (const float4*)(scores + (size_t)lrow * NM);
  for (int i = tid; i < NM / 4; i += 256) {
    const float4 v = r4[i];
    atomicAdd(&hist[fkey(v.x) >> 21], 1u);
    atomicAdd(&hist[fkey(v.y) >> 21], 1u);
    atomicAdd(&hist[fkey(v.z) >> 21], 1u);
    atomicAdd(&hist[fkey(v.w) >> 21], 1u);
  }
  __syncthreads();

  unsigned c = 0;
#pragma unroll
  for (int j = 0; j < 8; j++) c += hist[tid * 8 + j];
  csum[tid] = c;
  __syncthreads();
  if (tid == 0) {
    int acc = 0;
    int ch = 255;
    for (; ch > 0; --ch) {
      acc += (int)csum[ch];
      if (acc >= TOPK) break;
    }
    if (acc < TOPK && ch == 0) acc += (int)csum[0];
    int acc2 = acc - (int)csum[ch];
    int b = ch * 8 + 7;
    for (; b > ch * 8; --b) {
      acc2 += (int)hist[b];
      if (acc2 >= TOPK) break;
    }
    bstar_s = b;
  }
  __syncthreads();
  const unsigned bstar = (unsigned)bstar_s;

  for (int i = tid; i < NM / 4; i += 256) {
    const float4 v = r4[i];
    unsigned k0 = fkey(v.x), k1 = fkey(v.y), k2 = fkey(v.z), k3 = fkey(v.w);
    if ((k0 >> 21) >= bstar) { int p = atomicAdd(&cnt_s, 1); if (p < CAP) { ckey[p] = k0; cidx[p] = i * 4; } }
    if ((k1 >> 21) >= bstar) { int p = atomicAdd(&cnt_s, 1); if (p < CAP) { ckey[p] = k1; cidx[p] = i * 4 + 1; } }
    if ((k2 >> 21) >= bstar) { int p = atomicAdd(&cnt_s, 1); if (p < CAP) { ckey[p] = k2; cidx[p] = i * 4 + 2; } }
    if ((k3 >> 21) >= bstar) { int p = atomicAdd(&cnt_s, 1); if (p < CAP) { ckey[p] = k3; cidx[p] = i * 4 + 3; } }
  }
  __syncthreads();

  if (tid < 64) {
    int n = cnt_s;
    if (n > CAP) n = CAP;
    for (int k = 0; k < TOPK; k++) {
      unsigned bk = 0, bi = 0xFFFFFFFFu;
      for (int j = tid; j < n; j += 64) {
        const unsigned kk = ckey[j];
        const unsigned ii = (unsigned)cidx[j];
        if (kk > bk || (kk == bk && ii < bi)) { bk = kk; bi = ii; }
      }
#pragma unroll
      for (int off = 32; off; off >>= 1) {
        const unsigned ok = __shfl_down(bk, off, 64);
        const unsigned oi = __shfl_down(bi, off, 64);
        if (ok > bk || (ok == bk && oi < bi)) { bk = ok; bi = oi; }
      }
      bk = __shfl(bk, 0, 64);
      bi = __shfl(bi, 0, 64);
      if (tid == 0) { okey[k] = bk; oidx[k] = (int)bi; }
      for (int j = tid; j < n; j += 64)
        if (ckey[j] == bk && (unsigned)cidx[j] == bi) ckey[j] = 0;
    }
  }
  __syncthreads();

  if (tid < TOPK) {
    const float T = fabsf(temp[0]);
    const float s = kinv(okey[tid]) * T;
    const float m = kinv(okey[0]) * T;   // sorted desc -> first is max
    const float e = __expf(s - m);
    float sum = e;
#pragma unroll
    for (int off = 16; off; off >>= 1) sum += __shfl_xor(sum, off, 32);
    attn[(size_t)grow * TOPK + tid] = e / sum;
    idx_out[(size_t)grow * TOPK + tid] = oidx[tid];
  }
}

// ---------- gather values + residual + LayerNorm ----------
__global__ __launch_bounds__(256) void gather_ln_k(const float* __restrict__ V,
                                                   const float* __restrict__ Q,
                                                   const float* __restrict__ gamma,
                                                   const float* __restrict__ beta,
                                                   const float* __restrict__ attn,
                                                   const int* __restrict__ idx,
                                                   float* __restrict__ out) {
  const int row = blockIdx.x, tid = threadIdx.x;
  __shared__ float a_s[TOPK];
  __shared__ int i_s[TOPK];
  __shared__ float redS[4], redQ[4];
  if (tid < TOPK) {
    a_s[tid] = attn[(size_t)row * TOPK + tid];
    i_s[tid] = idx[(size_t)row * TOPK + tid];
  }
  __syncthreads();
  float4 acc = {0.f, 0.f, 0.f, 0.f};
#pragma unroll 8
  for (int k = 0; k < TOPK; k++) {
    const float4 v = ((const float4*)(V + (size_t)i_s[k] * D))[tid];
    const float a = a_s[k];
    acc.x = fmaf(a, v.x, acc.x);
    acc.y = fmaf(a, v.y, acc.y);
    acc.z = fmaf(a, v.z, acc.z);
    acc.w = fmaf(a, v.w, acc.w);
  }
  const float4 q = ((const float4*)(Q + (size_t)row * D))[tid];
  float4 x = {acc.x + q.x, acc.y + q.y, acc.z + q.z, acc.w + q.w};
  float s = x.x + x.y + x.z + x.w;
  float ss = x.x * x.x + x.y * x.y + x.z * x.z + x.w * x.w;
#pragma unroll
  for (int off = 32; off; off >>= 1) {
    s += __shfl_xor(s, off, 64);
    ss += __shfl_xor(ss, off, 64);
  }
  const int wid = tid >> 6, lane = tid & 63;
  if (lane == 0) { redS[wid] = s; redQ[wid] = ss; }
  __syncthreads();
  const float S = redS[0] + redS[1] + redS[2] + redS[3];
  const float SS = redQ[0] + redQ[1] + redQ[2] + redQ[3];
  const float mu = S * (1.0f / D);
  const float var = SS * (1.0f / D) - mu * mu;
  const float rstd = rsqrtf(var + 1e-5f);
  const float4 g = ((const float4*)gamma)[tid];
  const float4 b = ((const float4*)beta)[tid];
  float4 o;
  o.x = (x.x - mu) * rstd * g.x + b.x;
  o.y = (x.y - mu) * rstd * g.y + b.y;
  o.z = (x.z - mu) * rstd * g.z + b.z;
  o.w = (x.w - mu) * rstd * g.w + b.w;
  ((float4*)(out + (size_t)row * D))[tid] = o;
}

extern "C" void kernel_launch(void* const* d_in, const int* in_sizes, int n_in,
                              void* d_out, int out_size, void* d_ws, size_t ws_size,
                              hipStream_t stream) {
  const float* Q = (const float*)d_in[0];
  const float* K = (const float*)d_in[1];
  const float* V = (const float*)d_in[2];
  const float* T = (const float*)d_in[3];
  const float* G = (const float*)d_in[4];
  const float* Bt = (const float*)d_in[5];
  float* out = (float*)d_out;
  float* attn = out + (size_t)NQ * D;

  char* ws = (char*)d_ws;
  const size_t off_qn = 0;
  const size_t off_kn = off_qn + (size_t)NQ * D * 2;                 // 16 MB
  const size_t off_idx = off_kn + (size_t)NM * D * 2;                // +64 MB
  const size_t off_sc = off_idx + (size_t)NQ * TOPK * sizeof(int);   // +1 MB
  ushort* qn = (ushort*)(ws + off_qn);
  ushort* kn = (ushort*)(ws + off_kn);
  int* idx = (int*)(ws + off_idx);
  float* scores = (float*)(ws + off_sc);

  const size_t avail = ws_size > off_sc ? ws_size - off_sc : 0;
  int slice = 1024;  // 128 MB f32 scores: L3-resident between gemm and topk
  while (slice > 128 && (size_t)slice * NM * 4ull > avail) slice >>= 1;

  norm_cast_k<<<NQ, 256, 0, stream>>>(Q, qn);
  norm_cast_k<<<NM, 256, 0, stream>>>(K, kn);

  for (int s0 = 0; s0 < NQ; s0 += slice) {
    gemm_qk<<<dim3(NM / 128, slice / 128), 256, 0, stream>>>(qn + (size_t)s0 * D, kn, scores);
    topk_k<<<slice, 256, 0, stream>>>(scores, s0, T, attn, idx);
  }
  gather_ln_k<<<NQ, 256, 0, stream>>>(V, Q, G, Bt, attn, idx, out);
}

// Round 2
// 1555.101 us; speedup vs baseline: 1.2023x; 1.2023x over previous
//
#include <hip/hip_runtime.h>
#include <hip/hip_bf16.h>

#define D 1024
#define NQ 8192
#define NM 32768
#define TOPK 32

typedef __attribute__((ext_vector_type(8))) __bf16 bf16x8;
typedef __attribute__((ext_vector_type(4))) float f32x4;

__device__ __forceinline__ void load_lds16(const void* g, void* l) {
  __builtin_amdgcn_global_load_lds(
      (const __attribute__((address_space(1))) void*)g,
      (__attribute__((address_space(3))) void*)l, 16, 0, 0);
}

__device__ __forceinline__ ushort f2bf(float f) {
  unsigned u = __float_as_uint(f);
  unsigned r = (u + 0x7FFFu + ((u >> 16) & 1u)) >> 16;
  return (ushort)r;
}

// ---------- row L2-normalize f32 -> bf16 ----------
__global__ __launch_bounds__(256) void norm_cast_k(const float* __restrict__ in,
                                                   ushort* __restrict__ out) {
  const int row = blockIdx.x;
  const int tid = threadIdx.x;
  const float4 v = ((const float4*)(in + (size_t)row * D))[tid];
  float ss = v.x * v.x + v.y * v.y + v.z * v.z + v.w * v.w;
#pragma unroll
  for (int off = 32; off; off >>= 1) ss += __shfl_xor(ss, off, 64);
  __shared__ float wsum[4];
  const int wid = tid >> 6, lane = tid & 63;
  if (lane == 0) wsum[wid] = ss;
  __syncthreads();
  const float tot = wsum[0] + wsum[1] + wsum[2] + wsum[3];
  const float inv = 1.0f / fmaxf(sqrtf(tot), 1e-12f);
  ushort4 o;
  o.x = f2bf(v.x * inv);
  o.y = f2bf(v.y * inv);
  o.z = f2bf(v.z * inv);
  o.w = f2bf(v.w * inv);
  ((ushort4*)(out + (size_t)row * D))[tid] = o;
}

// ---------- bf16 GEMM: C[r][c] = sum_k A[r][k]*B[c][k], bf16 C output ----------
__global__ __launch_bounds__(256) void gemm_qk(const ushort* __restrict__ A,   // [rows][1024]
                                               const ushort* __restrict__ B,   // [32768][1024]
                                               ushort* __restrict__ C) {       // [rows][32768] bf16
  __shared__ alignas(16) ushort As[128 * 32];
  __shared__ alignas(16) ushort Bs[128 * 32];
  const int tid = threadIdx.x;
  const int lane = tid & 63, wid = tid >> 6;
  const int bx = blockIdx.x, by = blockIdx.y;
  const int wr = wid >> 1, wc = wid & 1;

  f32x4 acc[4][4];
#pragma unroll
  for (int m = 0; m < 4; m++)
#pragma unroll
    for (int n = 0; n < 4; n++) acc[m][n] = f32x4{0.f, 0.f, 0.f, 0.f};

  const int r0 = tid >> 2;
  const int r1 = (tid + 256) >> 2;
  const int cb = (tid & 3) * 8;
  const ushort* gA0 = A + ((size_t)by * 128 + r0) * D + cb;
  const ushort* gA1 = A + ((size_t)by * 128 + r1) * D + cb;
  const ushort* gB0 = B + ((size_t)bx * 128 + r0) * D + cb;
  const ushort* gB1 = B + ((size_t)bx * 128 + r1) * D + cb;
  ushort* lA0 = As + wid * 64 * 8;
  ushort* lA1 = As + 256 * 8 + wid * 64 * 8;
  ushort* lB0 = Bs + wid * 64 * 8;
  ushort* lB1 = Bs + 256 * 8 + wid * 64 * 8;

  const int aoff = (wr * 64 + (lane & 15)) * 32 + (lane >> 4) * 8;
  const int boff = (wc * 64 + (lane & 15)) * 32 + (lane >> 4) * 8;

  for (int kk = 0; kk < D; kk += 32) {
    load_lds16(gA0 + kk, lA0);
    load_lds16(gA1 + kk, lA1);
    load_lds16(gB0 + kk, lB0);
    load_lds16(gB1 + kk, lB1);
    __syncthreads();
    bf16x8 af[4], bfv[4];
#pragma unroll
    for (int m = 0; m < 4; m++) af[m] = *(const bf16x8*)&As[aoff + m * 16 * 32];
#pragma unroll
    for (int n = 0; n < 4; n++) bfv[n] = *(const bf16x8*)&Bs[boff + n * 16 * 32];
#pragma unroll
    for (int m = 0; m < 4; m++)
#pragma unroll
      for (int n = 0; n < 4; n++)
        acc[m][n] = __builtin_amdgcn_mfma_f32_16x16x32_bf16(af[m], bfv[n], acc[m][n], 0, 0, 0);
    __syncthreads();
  }

  // C/D layout: row = (lane>>4)*4 + j, col = lane&15
  const size_t crow = (size_t)by * 128 + wr * 64 + ((lane >> 4) << 2);
  const size_t ccol = (size_t)bx * 128 + wc * 64 + (lane & 15);
#pragma unroll
  for (int m = 0; m < 4; m++)
#pragma unroll
    for (int n = 0; n < 4; n++)
#pragma unroll
      for (int j = 0; j < 4; j++)
        C[(crow + m * 16 + j) * (size_t)NM + ccol + n * 16] = f2bf(acc[m][n][j]);
}

// ---------- top-32 per row: register-resident bf16 keys, binary-search select ----------
#define CAP 320
__global__ __launch_bounds__(256) void topk_k(const ushort* __restrict__ scores, int row_base,
                                              const float* __restrict__ temp,
                                              float* __restrict__ attn,
                                              int* __restrict__ idx_out) {
  const int lrow = blockIdx.x;
  const int grow = row_base + lrow;
  const int tid = threadIdx.x;
  const int lane = tid & 63, wid = tid >> 6;
  __shared__ int red[4];
  __shared__ int cnt_s;
  __shared__ unsigned ckey[CAP];
  __shared__ int cidx[CAP];
  __shared__ unsigned okey[TOPK];
  __shared__ int oidx[TOPK];

  // load whole row into registers as packed monotonic 16-bit keys
  // key(u) = u ^ (sign? 0xFFFF : 0x8000)  -> unsigned order == float order
  const uint4* row4 = (const uint4*)(scores + (size_t)lrow * NM);
  unsigned kreg[64];
#pragma unroll
  for (int j = 0; j < 16; ++j) {
    const uint4 w = row4[tid + 256 * j];
    const unsigned wv[4] = {w.x, w.y, w.z, w.w};
#pragma unroll
    for (int p = 0; p < 4; ++p) {
      const unsigned u = wv[p];
      const unsigned m = (u >> 15) & 0x00010001u;
      kreg[j * 4 + p] = u ^ (m * 0x7FFFu + 0x80008000u);
    }
  }

  // binary search for the 32nd-largest 16-bit key (exact, with duplicates)
  int lo = 0, hi = 65535;
  for (int it = 0; it < 16; ++it) {
    const unsigned mid = (unsigned)((lo + hi + 1) >> 1);
    int c = 0;
#pragma unroll
    for (int r = 0; r < 64; ++r) {
      c += (int)((kreg[r] & 0xFFFFu) >= mid);
      c += (int)((kreg[r] >> 16) >= mid);
    }
#pragma unroll
    for (int off = 32; off; off >>= 1) c += __shfl_xor(c, off, 64);
    if (lane == 0) red[wid] = c;
    __syncthreads();
    c = red[0] + red[1] + red[2] + red[3];
    __syncthreads();
    if (c >= TOPK) lo = (int)mid; else hi = (int)mid - 1;
  }
  const unsigned t32 = (unsigned)lo;

  if (tid == 0) cnt_s = 0;
  __syncthreads();

  // collect candidates (count in [32, 32+dups))
#pragma unroll
  for (int j = 0; j < 16; ++j) {
#pragma unroll
    for (int p = 0; p < 4; ++p) {
      const unsigned kk = kreg[j * 4 + p];
      const unsigned klo = kk & 0xFFFFu, khi = kk >> 16;
      const int base = (tid + 256 * j) * 8 + p * 2;
      if (klo >= t32) { const int q = atomicAdd(&cnt_s, 1); if (q < CAP) { ckey[q] = klo; cidx[q] = base; } }
      if (khi >= t32) { const int q = atomicAdd(&cnt_s, 1); if (q < CAP) { ckey[q] = khi; cidx[q] = base + 1; } }
    }
  }
  __syncthreads();

  // one-wave extraction: 32x argmax by (key desc, idx asc)
  if (tid < 64) {
    int n = cnt_s;
    if (n > CAP) n = CAP;
    for (int k = 0; k < TOPK; ++k) {
      unsigned bk = 0, bi = 0xFFFFFFFFu;
      for (int j = tid; j < n; j += 64) {
        const unsigned kk = ckey[j];
        const unsigned ii = (unsigned)cidx[j];
        if (kk > bk || (kk == bk && ii < bi)) { bk = kk; bi = ii; }
      }
#pragma unroll
      for (int off = 32; off; off >>= 1) {
        const unsigned ok = __shfl_down(bk, off, 64);
        const unsigned oi = __shfl_down(bi, off, 64);
        if (ok > bk || (ok == bk && oi < bi)) { bk = ok; bi = oi; }
      }
      bk = __shfl(bk, 0, 64);
      bi = __shfl(bi, 0, 64);
      if (tid == 0) { okey[k] = bk; oidx[k] = (int)bi; }
      for (int j = tid; j < n; j += 64)
        if (ckey[j] == bk && cidx[j] == (int)bi) ckey[j] = 0;
    }
  }
  __syncthreads();

  if (tid < TOPK) {
    const float T = fabsf(temp[0]);
    const unsigned k0 = okey[tid];
    const unsigned u0 = (k0 & 0x8000u) ? (k0 ^ 0x8000u) : (k0 ^ 0xFFFFu);
    const unsigned km = okey[0];
    const unsigned um = (km & 0x8000u) ? (km ^ 0x8000u) : (km ^ 0xFFFFu);
    const float s = __uint_as_float(u0 << 16) * T;
    const float mx = __uint_as_float(um << 16) * T;   // sorted desc -> first is max
    const float e = __expf(s - mx);
    float sum = e;
#pragma unroll
    for (int off = 16; off; off >>= 1) sum += __shfl_xor(sum, off, 32);
    attn[(size_t)grow * TOPK + tid] = e / sum;
    idx_out[(size_t)grow * TOPK + tid] = oidx[tid];
  }
}

// ---------- gather values + residual + LayerNorm ----------
__global__ __launch_bounds__(256) void gather_ln_k(const float* __restrict__ V,
                                                   const float* __restrict__ Q,
                                                   const float* __restrict__ gamma,
                                                   const float* __restrict__ beta,
                                                   const float* __restrict__ attn,
                                                   const int* __restrict__ idx,
                                                   float* __restrict__ out) {
  const int row = blockIdx.x, tid = threadIdx.x;
  __shared__ float a_s[TOPK];
  __shared__ int i_s[TOPK];
  __shared__ float redS[4], redQ[4];
  if (tid < TOPK) {
    a_s[tid] = attn[(size_t)row * TOPK + tid];
    i_s[tid] = idx[(size_t)row * TOPK + tid];
  }
  __syncthreads();
  float4 acc = {0.f, 0.f, 0.f, 0.f};
#pragma unroll
  for (int kb = 0; kb < TOPK; kb += 8) {
    float4 v[8];
#pragma unroll
    for (int u = 0; u < 8; ++u)
      v[u] = ((const float4*)(V + (size_t)i_s[kb + u] * D))[tid];
#pragma unroll
    for (int u = 0; u < 8; ++u) {
      const float a = a_s[kb + u];
      acc.x = fmaf(a, v[u].x, acc.x);
      acc.y = fmaf(a, v[u].y, acc.y);
      acc.z = fmaf(a, v[u].z, acc.z);
      acc.w = fmaf(a, v[u].w, acc.w);
    }
  }
  const float4 q = ((const float4*)(Q + (size_t)row * D))[tid];
  float4 x = {acc.x + q.x, acc.y + q.y, acc.z + q.z, acc.w + q.w};
  float s = x.x + x.y + x.z + x.w;
  float ss = x.x * x.x + x.y * x.y + x.z * x.z + x.w * x.w;
#pragma unroll
  for (int off = 32; off; off >>= 1) {
    s += __shfl_xor(s, off, 64);
    ss += __shfl_xor(ss, off, 64);
  }
  const int wid = tid >> 6, lane = tid & 63;
  if (lane == 0) { redS[wid] = s; redQ[wid] = ss; }
  __syncthreads();
  const float S = redS[0] + redS[1] + redS[2] + redS[3];
  const float SS = redQ[0] + redQ[1] + redQ[2] + redQ[3];
  const float mu = S * (1.0f / D);
  const float var = SS * (1.0f / D) - mu * mu;
  const float rstd = rsqrtf(var + 1e-5f);
  const float4 g = ((const float4*)gamma)[tid];
  const float4 b = ((const float4*)beta)[tid];
  float4 o;
  o.x = (x.x - mu) * rstd * g.x + b.x;
  o.y = (x.y - mu) * rstd * g.y + b.y;
  o.z = (x.z - mu) * rstd * g.z + b.z;
  o.w = (x.w - mu) * rstd * g.w + b.w;
  ((float4*)(out + (size_t)row * D))[tid] = o;
}

extern "C" void kernel_launch(void* const* d_in, const int* in_sizes, int n_in,
                              void* d_out, int out_size, void* d_ws, size_t ws_size,
                              hipStream_t stream) {
  const float* Q = (const float*)d_in[0];
  const float* K = (const float*)d_in[1];
  const float* V = (const float*)d_in[2];
  const float* T = (const float*)d_in[3];
  const float* G = (const float*)d_in[4];
  const float* Bt = (const float*)d_in[5];
  float* out = (float*)d_out;
  float* attn = out + (size_t)NQ * D;

  char* ws = (char*)d_ws;
  const size_t off_qn = 0;
  const size_t off_kn = off_qn + (size_t)NQ * D * 2;                 // 16 MB
  const size_t off_idx = off_kn + (size_t)NM * D * 2;                // +64 MB
  const size_t off_sc = off_idx + (size_t)NQ * TOPK * sizeof(int);   // +1 MB
  ushort* qn = (ushort*)(ws + off_qn);
  ushort* kn = (ushort*)(ws + off_kn);
  int* idx = (int*)(ws + off_idx);
  ushort* scores = (ushort*)(ws + off_sc);

  const size_t avail = ws_size > off_sc ? ws_size - off_sc : 0;
  int slice = 2048;  // 128 MB bf16 scores: L3-resident between gemm and topk
  while (slice > 128 && (size_t)slice * NM * 2ull > avail) slice >>= 1;

  norm_cast_k<<<NQ, 256, 0, stream>>>(Q, qn);
  norm_cast_k<<<NM, 256, 0, stream>>>(K, kn);

  for (int s0 = 0; s0 < NQ; s0 += slice) {
    gemm_qk<<<dim3(NM / 128, slice / 128), 256, 0, stream>>>(qn + (size_t)s0 * D, kn, scores);
    topk_k<<<slice, 256, 0, stream>>>(scores, s0, T, attn, idx);
  }
  gather_ln_k<<<NQ, 256, 0, stream>>>(V, Q, G, Bt, attn, idx, out);
}

// Round 3
// 1225.467 us; speedup vs baseline: 1.5257x; 1.2690x over previous
//
#include <hip/hip_runtime.h>
#include <hip/hip_bf16.h>

#define D 1024
#define NQ 8192
#define NM 32768
#define TOPK 32

typedef __attribute__((ext_vector_type(8))) __bf16 bf16x8;
typedef __attribute__((ext_vector_type(4))) float f32x4;

__device__ __forceinline__ void load_lds16(const void* g, void* l) {
  __builtin_amdgcn_global_load_lds(
      (const __attribute__((address_space(1))) void*)g,
      (__attribute__((address_space(3))) void*)l, 16, 0, 0);
}

__device__ __forceinline__ ushort f2bf(float f) {
  unsigned u = __float_as_uint(f);
  unsigned r = (u + 0x7FFFu + ((u >> 16) & 1u)) >> 16;
  return (ushort)r;
}

// ---------- row L2-normalize f32 -> bf16 ----------
__global__ __launch_bounds__(256) void norm_cast_k(const float* __restrict__ in,
                                                   ushort* __restrict__ out) {
  const int row = blockIdx.x;
  const int tid = threadIdx.x;
  const float4 v = ((const float4*)(in + (size_t)row * D))[tid];
  float ss = v.x * v.x + v.y * v.y + v.z * v.z + v.w * v.w;
#pragma unroll
  for (int off = 32; off; off >>= 1) ss += __shfl_xor(ss, off, 64);
  __shared__ float wsum[4];
  const int wid = tid >> 6, lane = tid & 63;
  if (lane == 0) wsum[wid] = ss;
  __syncthreads();
  const float tot = wsum[0] + wsum[1] + wsum[2] + wsum[3];
  const float inv = 1.0f / fmaxf(sqrtf(tot), 1e-12f);
  ushort4 o;
  o.x = f2bf(v.x * inv);
  o.y = f2bf(v.y * inv);
  o.z = f2bf(v.z * inv);
  o.w = f2bf(v.w * inv);
  ((ushort4*)(out + (size_t)row * D))[tid] = o;
}

// ---------- bf16 GEMM: C[r][c] = sum_k A[r][k]*B[c][k], bf16 C output ----------
__global__ __launch_bounds__(256) void gemm_qk(const ushort* __restrict__ A,
                                               const ushort* __restrict__ B,
                                               ushort* __restrict__ C) {
  __shared__ alignas(16) ushort As[128 * 32];
  __shared__ alignas(16) ushort Bs[128 * 32];
  const int tid = threadIdx.x;
  const int lane = tid & 63, wid = tid >> 6;
  const int bx = blockIdx.x, by = blockIdx.y;
  const int wr = wid >> 1, wc = wid & 1;

  f32x4 acc[4][4];
#pragma unroll
  for (int m = 0; m < 4; m++)
#pragma unroll
    for (int n = 0; n < 4; n++) acc[m][n] = f32x4{0.f, 0.f, 0.f, 0.f};

  const int r0 = tid >> 2;
  const int r1 = (tid + 256) >> 2;
  const int cb = (tid & 3) * 8;
  const ushort* gA0 = A + ((size_t)by * 128 + r0) * D + cb;
  const ushort* gA1 = A + ((size_t)by * 128 + r1) * D + cb;
  const ushort* gB0 = B + ((size_t)bx * 128 + r0) * D + cb;
  const ushort* gB1 = B + ((size_t)bx * 128 + r1) * D + cb;
  ushort* lA0 = As + wid * 64 * 8;
  ushort* lA1 = As + 256 * 8 + wid * 64 * 8;
  ushort* lB0 = Bs + wid * 64 * 8;
  ushort* lB1 = Bs + 256 * 8 + wid * 64 * 8;

  const int aoff = (wr * 64 + (lane & 15)) * 32 + (lane >> 4) * 8;
  const int boff = (wc * 64 + (lane & 15)) * 32 + (lane >> 4) * 8;

  for (int kk = 0; kk < D; kk += 32) {
    load_lds16(gA0 + kk, lA0);
    load_lds16(gA1 + kk, lA1);
    load_lds16(gB0 + kk, lB0);
    load_lds16(gB1 + kk, lB1);
    __syncthreads();
    bf16x8 af[4], bfv[4];
#pragma unroll
    for (int m = 0; m < 4; m++) af[m] = *(const bf16x8*)&As[aoff + m * 16 * 32];
#pragma unroll
    for (int n = 0; n < 4; n++) bfv[n] = *(const bf16x8*)&Bs[boff + n * 16 * 32];
#pragma unroll
    for (int m = 0; m < 4; m++)
#pragma unroll
      for (int n = 0; n < 4; n++)
        acc[m][n] = __builtin_amdgcn_mfma_f32_16x16x32_bf16(af[m], bfv[n], acc[m][n], 0, 0, 0);
    __syncthreads();
  }

  const size_t crow = (size_t)by * 128 + wr * 64 + ((lane >> 4) << 2);
  const size_t ccol = (size_t)bx * 128 + wc * 64 + (lane & 15);
#pragma unroll
  for (int m = 0; m < 4; m++)
#pragma unroll
    for (int n = 0; n < 4; n++)
#pragma unroll
      for (int j = 0; j < 4; j++)
        C[(crow + m * 16 + j) * (size_t)NM + ccol + n * 16] = f2bf(acc[m][n][j]);
}

// ---------- top-32: max -> near-max candidate filter -> 1-wave select ----------
#define CAP2 1024
__global__ __launch_bounds__(512) void topk_k(const ushort* __restrict__ scores, int row_base,
                                              const float* __restrict__ temp,
                                              float* __restrict__ attn,
                                              int* __restrict__ idx_out) {
  const int lrow = blockIdx.x;
  const int grow = row_base + lrow;
  const int tid = threadIdx.x;
  const int lane = tid & 63, wid = tid >> 6;
  __shared__ unsigned red[8];
  __shared__ int cnt_s;
  __shared__ unsigned ckey[CAP2];
  __shared__ unsigned cand64[64];
  __shared__ unsigned okey[TOPK];
  __shared__ int oidx[TOPK];

  // load 64 keys/thread as 32 packed monotonic u16 pairs
  const uint4* row4 = (const uint4*)(scores + (size_t)lrow * NM);
  unsigned kreg[32];
#pragma unroll
  for (int j = 0; j < 8; ++j) {
    const uint4 w = row4[tid + 512 * j];
    const unsigned wv[4] = {w.x, w.y, w.z, w.w};
#pragma unroll
    for (int p = 0; p < 4; ++p) {
      const unsigned u = wv[p];
      const unsigned m = (u >> 15) & 0x00010001u;
      kreg[j * 4 + p] = u ^ (m * 0x7FFFu + 0x80008000u);
    }
  }

  // per-thread packed max, then block max
  unsigned mhi = 0, mlo = 0;
#pragma unroll
  for (int r = 0; r < 32; ++r) {
    mhi = max(mhi, kreg[r] & 0xFFFF0000u);
    mlo = max(mlo, kreg[r] << 16);
  }
  unsigned tmax = max(mhi, mlo) >> 16;
#pragma unroll
  for (int off = 32; off; off >>= 1) tmax = max(tmax, __shfl_xor(tmax, off, 64));
  if (lane == 0) red[wid] = tmax;
  if (tid == 0) cnt_s = 0;
  __syncthreads();
  unsigned M = red[0];
#pragma unroll
  for (int w = 1; w < 8; ++w) M = max(M, red[w]);

  // collect candidates >= t0 into packed LDS list (key<<16 | (32767-idx))
  unsigned t0 = (M > 128) ? (M - 128) : 0u;
  int cnt = 0;
  for (int att = 0; att < 18; ++att) {
#pragma unroll
    for (int j = 0; j < 8; ++j) {
#pragma unroll
      for (int p = 0; p < 4; ++p) {
        const unsigned kk = kreg[j * 4 + p];
        const unsigned klo = kk & 0xFFFFu, khi = kk >> 16;
        const int base = (tid + 512 * j) * 8 + p * 2;
        if (klo >= t0) {
          const int q = atomicAdd(&cnt_s, 1);
          if (q < CAP2) ckey[q] = (klo << 16) | (unsigned)(32767 - base);
        }
        if (khi >= t0) {
          const int q = atomicAdd(&cnt_s, 1);
          if (q < CAP2) ckey[q] = (khi << 16) | (unsigned)(32767 - (base + 1));
        }
      }
    }
    __syncthreads();
    cnt = cnt_s;
    __syncthreads();
    if ((cnt >= TOPK && cnt <= CAP2) || att == 17) break;
    if (cnt < TOPK) t0 >>= 1;                    // widen (unexercised on bench data)
    else t0 = t0 + ((M - t0 + 1) >> 1);          // tighten toward M
    if (tid == 0) cnt_s = 0;
    __syncthreads();
  }
  const int n = min(cnt, CAP2);

  // single-wave: exact 32nd threshold by bisection over the candidate list
  if (tid < 64) {
    unsigned lo = t0, hi = M;
    while (lo < hi) {
      const unsigned mid = (lo + hi + 1) >> 1;
      int c = 0;
      for (int i = lane; i < n; i += 64) c += (int)((ckey[i] >> 16) >= mid);
#pragma unroll
      for (int off = 32; off; off >>= 1) c += __shfl_xor(c, off, 64);
      if (c >= TOPK) lo = mid; else hi = mid - 1;
    }
    const unsigned t32 = lo;
    int c32 = 0;
    for (int i = lane; i < n; i += 64) c32 += (int)((ckey[i] >> 16) >= t32);
#pragma unroll
    for (int off = 32; off; off >>= 1) c32 += __shfl_xor(c32, off, 64);

    if (c32 <= 64) {
      // ballot-compact qualifying candidates, then bitonic-64 sort (desc)
      cand64[lane] = 0;
      int base = 0;
      for (int r0 = 0; r0 < n; r0 += 64) {
        const int i = r0 + lane;
        const unsigned k = (i < n) ? ckey[i] : 0u;
        const bool p = (k >> 16) >= t32;
        const unsigned long long bm = __ballot(p);
        if (p) {
          const int pos = base + __popcll(bm & ((1ull << lane) - 1ull));
          if (pos < 64) cand64[pos] = k;
        }
        base += __popcll(bm);
      }
      unsigned v = cand64[lane];
#pragma unroll
      for (int k2 = 2; k2 <= 64; k2 <<= 1) {
#pragma unroll
        for (int j = k2 >> 1; j > 0; j >>= 1) {
          const unsigned o = __shfl_xor(v, j, 64);
          const bool lower = (lane & j) == 0;
          const bool descB = (lane & k2) == 0;
          const unsigned mx = v > o ? v : o;
          const unsigned mn = v > o ? o : v;
          v = (lower == descB) ? mx : mn;
        }
      }
      if (lane < TOPK) {
        okey[lane] = v >> 16;
        oidx[lane] = 32767 - (int)(v & 0x7FFFu);
      }
    } else {
      // fallback: 32-round extraction (rare: >64 ties at the boundary)
      for (int k = 0; k < TOPK; ++k) {
        unsigned bk = 0;
        for (int j = lane; j < n; j += 64) bk = max(bk, ckey[j]);
#pragma unroll
        for (int off = 32; off; off >>= 1) bk = max(bk, __shfl_xor(bk, off, 64));
        if (lane == 0) {
          okey[k] = bk >> 16;
          oidx[k] = 32767 - (int)(bk & 0x7FFFu);
        }
        for (int j = lane; j < n; j += 64)
          if (ckey[j] == bk) ckey[j] = 0;
      }
    }
  }
  __syncthreads();

  if (tid < TOPK) {
    const float T = fabsf(temp[0]);
    const unsigned k0 = okey[tid];
    const unsigned u0 = (k0 & 0x8000u) ? (k0 ^ 0x8000u) : (k0 ^ 0xFFFFu);
    const unsigned km = okey[0];
    const unsigned um = (km & 0x8000u) ? (km ^ 0x8000u) : (km ^ 0xFFFFu);
    const float s = __uint_as_float(u0 << 16) * T;
    const float mx = __uint_as_float(um << 16) * T;
    const float e = __expf(s - mx);
    float sum = e;
#pragma unroll
    for (int off = 16; off; off >>= 1) sum += __shfl_xor(sum, off, 32);
    attn[(size_t)grow * TOPK + tid] = e / sum;
    idx_out[(size_t)grow * TOPK + tid] = oidx[tid];
  }
}

// ---------- gather values + residual + LayerNorm ----------
__global__ __launch_bounds__(256) void gather_ln_k(const float* __restrict__ V,
                                                   const float* __restrict__ Q,
                                                   const float* __restrict__ gamma,
                                                   const float* __restrict__ beta,
                                                   const float* __restrict__ attn,
                                                   const int* __restrict__ idx,
                                                   float* __restrict__ out) {
  const int row = blockIdx.x, tid = threadIdx.x;
  __shared__ float a_s[TOPK];
  __shared__ int i_s[TOPK];
  __shared__ float redS[4], redQ[4];
  if (tid < TOPK) {
    a_s[tid] = attn[(size_t)row * TOPK + tid];
    i_s[tid] = idx[(size_t)row * TOPK + tid];
  }
  __syncthreads();
  float4 acc = {0.f, 0.f, 0.f, 0.f};
#pragma unroll
  for (int kb = 0; kb < TOPK; kb += 8) {
    float4 v[8];
#pragma unroll
    for (int u = 0; u < 8; ++u)
      v[u] = ((const float4*)(V + (size_t)i_s[kb + u] * D))[tid];
#pragma unroll
    for (int u = 0; u < 8; ++u) {
      const float a = a_s[kb + u];
      acc.x = fmaf(a, v[u].x, acc.x);
      acc.y = fmaf(a, v[u].y, acc.y);
      acc.z = fmaf(a, v[u].z, acc.z);
      acc.w = fmaf(a, v[u].w, acc.w);
    }
  }
  const float4 q = ((const float4*)(Q + (size_t)row * D))[tid];
  float4 x = {acc.x + q.x, acc.y + q.y, acc.z + q.z, acc.w + q.w};
  float s = x.x + x.y + x.z + x.w;
  float ss = x.x * x.x + x.y * x.y + x.z * x.z + x.w * x.w;
#pragma unroll
  for (int off = 32; off; off >>= 1) {
    s += __shfl_xor(s, off, 64);
    ss += __shfl_xor(ss, off, 64);
  }
  const int wid = tid >> 6, lane = tid & 63;
  if (lane == 0) { redS[wid] = s; redQ[wid] = ss; }
  __syncthreads();
  const float S = redS[0] + redS[1] + redS[2] + redS[3];
  const float SS = redQ[0] + redQ[1] + redQ[2] + redQ[3];
  const float mu = S * (1.0f / D);
  const float var = SS * (1.0f / D) - mu * mu;
  const float rstd = rsqrtf(var + 1e-5f);
  const float4 g = ((const float4*)gamma)[tid];
  const float4 b = ((const float4*)beta)[tid];
  float4 o;
  o.x = (x.x - mu) * rstd * g.x + b.x;
  o.y = (x.y - mu) * rstd * g.y + b.y;
  o.z = (x.z - mu) * rstd * g.z + b.z;
  o.w = (x.w - mu) * rstd * g.w + b.w;
  ((float4*)(out + (size_t)row * D))[tid] = o;
}

extern "C" void kernel_launch(void* const* d_in, const int* in_sizes, int n_in,
                              void* d_out, int out_size, void* d_ws, size_t ws_size,
                              hipStream_t stream) {
  const float* Q = (const float*)d_in[0];
  const float* K = (const float*)d_in[1];
  const float* V = (const float*)d_in[2];
  const float* T = (const float*)d_in[3];
  const float* G = (const float*)d_in[4];
  const float* Bt = (const float*)d_in[5];
  float* out = (float*)d_out;
  float* attn = out + (size_t)NQ * D;

  char* ws = (char*)d_ws;
  const size_t off_qn = 0;
  const size_t off_kn = off_qn + (size_t)NQ * D * 2;
  const size_t off_idx = off_kn + (size_t)NM * D * 2;
  const size_t off_sc = off_idx + (size_t)NQ * TOPK * sizeof(int);
  ushort* qn = (ushort*)(ws + off_qn);
  ushort* kn = (ushort*)(ws + off_kn);
  int* idx = (int*)(ws + off_idx);
  ushort* scores = (ushort*)(ws + off_sc);

  const size_t avail = ws_size > off_sc ? ws_size - off_sc : 0;
  int slice = 2048;
  while (slice > 128 && (size_t)slice * NM * 2ull > avail) slice >>= 1;

  norm_cast_k<<<NQ, 256, 0, stream>>>(Q, qn);
  norm_cast_k<<<NM, 256, 0, stream>>>(K, kn);

  for (int s0 = 0; s0 < NQ; s0 += slice) {
    gemm_qk<<<dim3(NM / 128, slice / 128), 256, 0, stream>>>(qn + (size_t)s0 * D, kn, scores);
    topk_k<<<slice, 512, 0, stream>>>(scores, s0, T, attn, idx);
  }
  gather_ln_k<<<NQ, 256, 0, stream>>>(V, Q, G, Bt, attn, idx, out);
}

// Round 4
// 1096.650 us; speedup vs baseline: 1.7049x; 1.1175x over previous
//
#include <hip/hip_runtime.h>
#include <hip/hip_bf16.h>

#define D 1024
#define NQ 8192
#define NM 32768
#define TOPK 32

typedef __attribute__((ext_vector_type(8))) __bf16 bf16x8;
typedef __attribute__((ext_vector_type(4))) float f32x4;

__device__ __forceinline__ void load_lds16(const void* g, void* l) {
  __builtin_amdgcn_global_load_lds(
      (const __attribute__((address_space(1))) void*)g,
      (__attribute__((address_space(3))) void*)l, 16, 0, 0);
}

__device__ __forceinline__ ushort f2bf(float f) {
  unsigned u = __float_as_uint(f);
  unsigned r = (u + 0x7FFFu + ((u >> 16) & 1u)) >> 16;
  return (ushort)r;
}

// ---------- row L2-normalize f32 -> bf16 ----------
__global__ __launch_bounds__(256) void norm_cast_k(const float* __restrict__ in,
                                                   ushort* __restrict__ out) {
  const int row = blockIdx.x;
  const int tid = threadIdx.x;
  const float4 v = ((const float4*)(in + (size_t)row * D))[tid];
  float ss = v.x * v.x + v.y * v.y + v.z * v.z + v.w * v.w;
#pragma unroll
  for (int off = 32; off; off >>= 1) ss += __shfl_xor(ss, off, 64);
  __shared__ float wsum[4];
  const int wid = tid >> 6, lane = tid & 63;
  if (lane == 0) wsum[wid] = ss;
  __syncthreads();
  const float tot = wsum[0] + wsum[1] + wsum[2] + wsum[3];
  const float inv = 1.0f / fmaxf(sqrtf(tot), 1e-12f);
  ushort4 o;
  o.x = f2bf(v.x * inv);
  o.y = f2bf(v.y * inv);
  o.z = f2bf(v.z * inv);
  o.w = f2bf(v.w * inv);
  ((ushort4*)(out + (size_t)row * D))[tid] = o;
}

// ---------- 256x256 deep-pipelined bf16 GEMM (T1+T2+T3/T4+T5) ----------
// BK=32, 4-slot LDS ring (128 KiB), stage tile t+3 during tile t,
// counted vmcnt(8) at tile boundary, raw s_barrier, setprio around MFMA.
#define SLOTU 8192  // ushorts per operand per ring slot (256x32)

__global__ __launch_bounds__(512, 2) void gemm256(const ushort* __restrict__ A,
                                                  const ushort* __restrict__ B,
                                                  ushort* __restrict__ C,
                                                  int nby) {
  __shared__ alignas(16) ushort As[4 * SLOTU];
  __shared__ alignas(16) ushort Bs[4 * SLOTU];
  const int tid = threadIdx.x;
  const int lane = tid & 63, wid = tid >> 6;

  // T1: bijective XCD swizzle on flat grid; wg = bx*nby + by  (B-panel chunks/XCD)
  const int nwg = (int)gridDim.x;
  const int q = nwg >> 3, r = nwg & 7;
  const int xcd = (int)blockIdx.x & 7, pos = (int)blockIdx.x >> 3;
  const int wg = (xcd < r ? xcd * (q + 1) : r * (q + 1) + (xcd - r) * q) + pos;
  const int bx = wg / nby, by = wg % nby;

  const int wr = wid >> 2, wc = wid & 3;  // 2 x 4 waves; each owns 128x64 of C

  f32x4 acc[8][4];
#pragma unroll
  for (int m = 0; m < 8; m++)
#pragma unroll
    for (int n = 0; n < 4; n++) acc[m][n] = f32x4{0.f, 0.f, 0.f, 0.f};

  // staging: wave stages stripes j0,j1 (16 rows x 32 cols each) of A and B.
  // T2: global source pre-swizzled (kb ^= (row>>1)&3); LDS dest linear.
  const int j0 = wid * 2, j1 = wid * 2 + 1;
  const int srow = lane >> 2;
  const int skb = (lane & 3) ^ ((lane >> 3) & 3);
  const ushort* gA0 = A + ((size_t)by * 256 + 16 * j0 + srow) * D + skb * 8;
  const ushort* gA1 = A + ((size_t)by * 256 + 16 * j1 + srow) * D + skb * 8;
  const ushort* gB0 = B + ((size_t)bx * 256 + 16 * j0 + srow) * D + skb * 8;
  const ushort* gB1 = B + ((size_t)bx * 256 + 16 * j1 + srow) * D + skb * 8;
  ushort* const lA0 = As + j0 * 512;
  ushort* const lA1 = As + j1 * 512;
  ushort* const lB0 = Bs + j0 * 512;
  ushort* const lB1 = Bs + j1 * 512;

  // fragment reads apply the same swizzle on the k-block
  const int kbx = ((lane >> 4) ^ ((lane >> 1) & 3)) * 8;
  const int a_r0 = wr * 128 + (lane & 15);
  const int b_r0 = wc * 64 + (lane & 15);

  // prologue: stage tiles 0..2 (12 loads/thread), wait tile 0 (keep 8 in flight)
#pragma unroll
  for (int t = 0; t < 3; ++t) {
    const int ss = t * SLOTU;
    load_lds16(gA0 + t * 32, lA0 + ss);
    load_lds16(gA1 + t * 32, lA1 + ss);
    load_lds16(gB0 + t * 32, lB0 + ss);
    load_lds16(gB1 + t * 32, lB1 + ss);
  }
  asm volatile("s_waitcnt vmcnt(8)" ::: "memory");
  __builtin_amdgcn_s_barrier();

#pragma unroll 1
  for (int t = 0; t < 32; ++t) {
    const int sb = (t & 3) * SLOTU;
    bf16x8 afr[4], bfr[4];
    // ---- phase A: frags for m=0..3 + all B frags; stage A-stripes of t+3
#pragma unroll
    for (int m = 0; m < 4; ++m)
      afr[m] = *(const bf16x8*)&As[sb + (a_r0 + m * 16) * 32 + kbx];
#pragma unroll
    for (int n = 0; n < 4; ++n)
      bfr[n] = *(const bf16x8*)&Bs[sb + (b_r0 + n * 16) * 32 + kbx];
    if (t < 29) {
      const int ss = ((t + 3) & 3) * SLOTU;
      load_lds16(gA0 + (t + 3) * 32, lA0 + ss);
      load_lds16(gA1 + (t + 3) * 32, lA1 + ss);
    }
    __builtin_amdgcn_s_barrier();
    __builtin_amdgcn_s_setprio(1);
#pragma unroll
    for (int m = 0; m < 4; ++m)
#pragma unroll
      for (int n = 0; n < 4; ++n)
        acc[m][n] = __builtin_amdgcn_mfma_f32_16x16x32_bf16(afr[m], bfr[n], acc[m][n], 0, 0, 0);
    __builtin_amdgcn_s_setprio(0);
    __builtin_amdgcn_s_barrier();
    // ---- phase B: frags for m=4..7 (B frags reused); stage B-stripes of t+3
#pragma unroll
    for (int m = 0; m < 4; ++m)
      afr[m] = *(const bf16x8*)&As[sb + (a_r0 + 64 + m * 16) * 32 + kbx];
    if (t < 29) {
      const int ss = ((t + 3) & 3) * SLOTU;
      load_lds16(gB0 + (t + 3) * 32, lB0 + ss);
      load_lds16(gB1 + (t + 3) * 32, lB1 + ss);
    }
    __builtin_amdgcn_s_barrier();
    __builtin_amdgcn_s_setprio(1);
#pragma unroll
    for (int m = 0; m < 4; ++m)
#pragma unroll
      for (int n = 0; n < 4; ++n)
        acc[m + 4][n] = __builtin_amdgcn_mfma_f32_16x16x32_bf16(afr[m], bfr[n], acc[m + 4][n], 0, 0, 0);
    __builtin_amdgcn_s_setprio(0);
    // tile boundary: counted wait (tiles t+2,t+3 stay in flight); drain only at tail
    if (t < 29) asm volatile("s_waitcnt vmcnt(8)" ::: "memory");
    else if (t == 29) asm volatile("s_waitcnt vmcnt(4)" ::: "memory");
    else if (t == 30) asm volatile("s_waitcnt vmcnt(0)" ::: "memory");
    __builtin_amdgcn_s_barrier();
  }

  // C/D layout: row = (lane>>4)*4 + j, col = lane&15
  const size_t crow = (size_t)by * 256 + wr * 128 + ((lane >> 4) << 2);
  const size_t ccol = (size_t)bx * 256 + wc * 64 + (lane & 15);
#pragma unroll
  for (int m = 0; m < 8; m++)
#pragma unroll
    for (int n = 0; n < 4; n++)
#pragma unroll
      for (int j = 0; j < 4; j++)
        C[(crow + m * 16 + j) * (size_t)NM + ccol + n * 16] = f2bf(acc[m][n][j]);
}

// ---------- top-32: max -> near-max candidate filter -> 1-wave select ----------
#define CAP2 1024
__global__ __launch_bounds__(512) void topk_k(const ushort* __restrict__ scores, int row_base,
                                              const float* __restrict__ temp,
                                              float* __restrict__ attn,
                                              int* __restrict__ idx_out) {
  const int lrow = blockIdx.x;
  const int grow = row_base + lrow;
  const int tid = threadIdx.x;
  const int lane = tid & 63, wid = tid >> 6;
  __shared__ unsigned red[8];
  __shared__ int cnt_s;
  __shared__ unsigned ckey[CAP2];
  __shared__ unsigned cand64[64];
  __shared__ unsigned okey[TOPK];
  __shared__ int oidx[TOPK];

  const uint4* row4 = (const uint4*)(scores + (size_t)lrow * NM);
  unsigned kreg[32];
#pragma unroll
  for (int j = 0; j < 8; ++j) {
    const uint4 w = row4[tid + 512 * j];
    const unsigned wv[4] = {w.x, w.y, w.z, w.w};
#pragma unroll
    for (int p = 0; p < 4; ++p) {
      const unsigned u = wv[p];
      const unsigned m = (u >> 15) & 0x00010001u;
      kreg[j * 4 + p] = u ^ (m * 0x7FFFu + 0x80008000u);
    }
  }

  unsigned mhi = 0, mlo = 0;
#pragma unroll
  for (int r = 0; r < 32; ++r) {
    mhi = max(mhi, kreg[r] & 0xFFFF0000u);
    mlo = max(mlo, kreg[r] << 16);
  }
  unsigned tmax = max(mhi, mlo) >> 16;
#pragma unroll
  for (int off = 32; off; off >>= 1) tmax = max(tmax, __shfl_xor(tmax, off, 64));
  if (lane == 0) red[wid] = tmax;
  if (tid == 0) cnt_s = 0;
  __syncthreads();
  unsigned M = red[0];
#pragma unroll
  for (int w = 1; w < 8; ++w) M = max(M, red[w]);

  unsigned t0 = (M > 128) ? (M - 128) : 0u;
  int cnt = 0;
  for (int att = 0; att < 18; ++att) {
#pragma unroll
    for (int j = 0; j < 8; ++j) {
#pragma unroll
      for (int p = 0; p < 4; ++p) {
        const unsigned kk = kreg[j * 4 + p];
        const unsigned klo = kk & 0xFFFFu, khi = kk >> 16;
        const int base = (tid + 512 * j) * 8 + p * 2;
        if (klo >= t0) {
          const int q = atomicAdd(&cnt_s, 1);
          if (q < CAP2) ckey[q] = (klo << 16) | (unsigned)(32767 - base);
        }
        if (khi >= t0) {
          const int q = atomicAdd(&cnt_s, 1);
          if (q < CAP2) ckey[q] = (khi << 16) | (unsigned)(32767 - (base + 1));
        }
      }
    }
    __syncthreads();
    cnt = cnt_s;
    __syncthreads();
    if ((cnt >= TOPK && cnt <= CAP2) || att == 17) break;
    if (cnt < TOPK) t0 >>= 1;
    else t0 = t0 + ((M - t0 + 1) >> 1);
    if (tid == 0) cnt_s = 0;
    __syncthreads();
  }
  const int n = min(cnt, CAP2);

  if (tid < 64) {
    unsigned lo = t0, hi = M;
    while (lo < hi) {
      const unsigned mid = (lo + hi + 1) >> 1;
      int c = 0;
      for (int i = lane; i < n; i += 64) c += (int)((ckey[i] >> 16) >= mid);
#pragma unroll
      for (int off = 32; off; off >>= 1) c += __shfl_xor(c, off, 64);
      if (c >= TOPK) lo = mid; else hi = mid - 1;
    }
    const unsigned t32 = lo;
    int c32 = 0;
    for (int i = lane; i < n; i += 64) c32 += (int)((ckey[i] >> 16) >= t32);
#pragma unroll
    for (int off = 32; off; off >>= 1) c32 += __shfl_xor(c32, off, 64);

    if (c32 <= 64) {
      cand64[lane] = 0;
      int base = 0;
      for (int r0 = 0; r0 < n; r0 += 64) {
        const int i = r0 + lane;
        const unsigned k = (i < n) ? ckey[i] : 0u;
        const bool p = (k >> 16) >= t32;
        const unsigned long long bm = __ballot(p);
        if (p) {
          const int pos = base + __popcll(bm & ((1ull << lane) - 1ull));
          if (pos < 64) cand64[pos] = k;
        }
        base += __popcll(bm);
      }
      unsigned v = cand64[lane];
#pragma unroll
      for (int k2 = 2; k2 <= 64; k2 <<= 1) {
#pragma unroll
        for (int j = k2 >> 1; j > 0; j >>= 1) {
          const unsigned o = __shfl_xor(v, j, 64);
          const bool lower = (lane & j) == 0;
          const bool descB = (lane & k2) == 0;
          const unsigned mx = v > o ? v : o;
          const unsigned mn = v > o ? o : v;
          v = (lower == descB) ? mx : mn;
        }
      }
      if (lane < TOPK) {
        okey[lane] = v >> 16;
        oidx[lane] = 32767 - (int)(v & 0x7FFFu);
      }
    } else {
      for (int k = 0; k < TOPK; ++k) {
        unsigned bk = 0;
        for (int j = lane; j < n; j += 64) bk = max(bk, ckey[j]);
#pragma unroll
        for (int off = 32; off; off >>= 1) bk = max(bk, __shfl_xor(bk, off, 64));
        if (lane == 0) {
          okey[k] = bk >> 16;
          oidx[k] = 32767 - (int)(bk & 0x7FFFu);
        }
        for (int j = lane; j < n; j += 64)
          if (ckey[j] == bk) ckey[j] = 0;
      }
    }
  }
  __syncthreads();

  if (tid < TOPK) {
    const float T = fabsf(temp[0]);
    const unsigned k0 = okey[tid];
    const unsigned u0 = (k0 & 0x8000u) ? (k0 ^ 0x8000u) : (k0 ^ 0xFFFFu);
    const unsigned km = okey[0];
    const unsigned um = (km & 0x8000u) ? (km ^ 0x8000u) : (km ^ 0xFFFFu);
    const float s = __uint_as_float(u0 << 16) * T;
    const float mx = __uint_as_float(um << 16) * T;
    const float e = __expf(s - mx);
    float sum = e;
#pragma unroll
    for (int off = 16; off; off >>= 1) sum += __shfl_xor(sum, off, 32);
    attn[(size_t)grow * TOPK + tid] = e / sum;
    idx_out[(size_t)grow * TOPK + tid] = oidx[tid];
  }
}

// ---------- gather values + residual + LayerNorm ----------
__global__ __launch_bounds__(256) void gather_ln_k(const float* __restrict__ V,
                                                   const float* __restrict__ Q,
                                                   const float* __restrict__ gamma,
                                                   const float* __restrict__ beta,
                                                   const float* __restrict__ attn,
                                                   const int* __restrict__ idx,
                                                   float* __restrict__ out) {
  const int row = blockIdx.x, tid = threadIdx.x;
  __shared__ float a_s[TOPK];
  __shared__ int i_s[TOPK];
  __shared__ float redS[4], redQ[4];
  if (tid < TOPK) {
    a_s[tid] = attn[(size_t)row * TOPK + tid];
    i_s[tid] = idx[(size_t)row * TOPK + tid];
  }
  __syncthreads();
  float4 acc = {0.f, 0.f, 0.f, 0.f};
#pragma unroll
  for (int kb = 0; kb < TOPK; kb += 8) {
    float4 v[8];
#pragma unroll
    for (int u = 0; u < 8; ++u)
      v[u] = ((const float4*)(V + (size_t)i_s[kb + u] * D))[tid];
#pragma unroll
    for (int u = 0; u < 8; ++u) {
      const float a = a_s[kb + u];
      acc.x = fmaf(a, v[u].x, acc.x);
      acc.y = fmaf(a, v[u].y, acc.y);
      acc.z = fmaf(a, v[u].z, acc.z);
      acc.w = fmaf(a, v[u].w, acc.w);
    }
  }
  const float4 q = ((const float4*)(Q + (size_t)row * D))[tid];
  float4 x = {acc.x + q.x, acc.y + q.y, acc.z + q.z, acc.w + q.w};
  float s = x.x + x.y + x.z + x.w;
  float ss = x.x * x.x + x.y * x.y + x.z * x.z + x.w * x.w;
#pragma unroll
  for (int off = 32; off; off >>= 1) {
    s += __shfl_xor(s, off, 64);
    ss += __shfl_xor(ss, off, 64);
  }
  const int wid = tid >> 6, lane = tid & 63;
  if (lane == 0) { redS[wid] = s; redQ[wid] = ss; }
  __syncthreads();
  const float S = redS[0] + redS[1] + redS[2] + redS[3];
  const float SS = redQ[0] + redQ[1] + redQ[2] + redQ[3];
  const float mu = S * (1.0f / D);
  const float var = SS * (1.0f / D) - mu * mu;
  const float rstd = rsqrtf(var + 1e-5f);
  const float4 g = ((const float4*)gamma)[tid];
  const float4 b = ((const float4*)beta)[tid];
  float4 o;
  o.x = (x.x - mu) * rstd * g.x + b.x;
  o.y = (x.y - mu) * rstd * g.y + b.y;
  o.z = (x.z - mu) * rstd * g.z + b.z;
  o.w = (x.w - mu) * rstd * g.w + b.w;
  ((float4*)(out + (size_t)row * D))[tid] = o;
}

extern "C" void kernel_launch(void* const* d_in, const int* in_sizes, int n_in,
                              void* d_out, int out_size, void* d_ws, size_t ws_size,
                              hipStream_t stream) {
  const float* Q = (const float*)d_in[0];
  const float* K = (const float*)d_in[1];
  const float* V = (const float*)d_in[2];
  const float* T = (const float*)d_in[3];
  const float* G = (const float*)d_in[4];
  const float* Bt = (const float*)d_in[5];
  float* out = (float*)d_out;
  float* attn = out + (size_t)NQ * D;

  char* ws = (char*)d_ws;
  const size_t off_qn = 0;
  const size_t off_kn = off_qn + (size_t)NQ * D * 2;
  const size_t off_idx = off_kn + (size_t)NM * D * 2;
  const size_t off_sc = off_idx + (size_t)NQ * TOPK * sizeof(int);
  ushort* qn = (ushort*)(ws + off_qn);
  ushort* kn = (ushort*)(ws + off_kn);
  int* idx = (int*)(ws + off_idx);
  ushort* scores = (ushort*)(ws + off_sc);

  const size_t avail = ws_size > off_sc ? ws_size - off_sc : 0;
  int slice = 2048;
  while (slice > 256 && (size_t)slice * NM * 2ull > avail) slice >>= 1;

  norm_cast_k<<<NQ, 256, 0, stream>>>(Q, qn);
  norm_cast_k<<<NM, 256, 0, stream>>>(K, kn);

  const int nbx = NM / 256;
  for (int s0 = 0; s0 < NQ; s0 += slice) {
    const int nby = slice / 256;
    gemm256<<<nbx * nby, 512, 0, stream>>>(qn + (size_t)s0 * D, kn, scores, nby);
    topk_k<<<slice, 512, 0, stream>>>(scores, s0, T, attn, idx);
  }
  gather_ln_k<<<NQ, 256, 0, stream>>>(V, Q, G, Bt, attn, idx, out);
}